// Round 2
// 8620.934 us; speedup vs baseline: 1.5263x; 1.5263x over previous
//
#include <hip/hip_runtime.h>
#include <math.h>

// Problem dims (fixed)
#define Bv   4
#define Sv   512
#define Hv   1024
#define Nv   128
#define Lv   6
#define Vv   32000
#define NHv  8
#define FFv  4096
#define DHv  128
#define Mv   (Bv*Sv)   // 2048 token rows

typedef unsigned short u16;
typedef __bf16  bf16x8 __attribute__((ext_vector_type(8)));
typedef unsigned short u16x8 __attribute__((ext_vector_type(8)));
typedef float   f32x4  __attribute__((ext_vector_type(4)));

// LDS tile row stride in u16 units: 40 (=80B). Rows stay 16B-aligned
// (40*2=80, 80%16==0); fragment reads at stride 80B hit banks
// (20*r+4*c)%32 -> 8 distinct banks x 2 lanes = 2-way = free (m136).
#define LDW 40

// bf16 (as ushort) <-> fp32
__device__ __forceinline__ float b2f(u16 u) {
    union { unsigned int i; float f; } v; v.i = ((unsigned int)u) << 16; return v.f;
}
__device__ __forceinline__ u16 f2b(float f) {
    union { float f; unsigned int i; } v; v.f = f;
    unsigned int x = v.i;
    return (u16)((x + 0x7fffu + ((x >> 16) & 1u)) >> 16);   // RNE
}

// ---------------------------------------------------------------------------
// On-device dtype probe (typo fixed: second pair tests !sane16(v.z)).
// Requires blockDim >= 128. Returns 1 if bf16.
// ---------------------------------------------------------------------------
__device__ __forceinline__ int sane16(u16 u) {
    if (u == 0) return 1;
    int e = (u >> 7) & 0xFF;
    return (e >= 0x66 && e <= 0x8F);
}
__device__ __forceinline__ int probe_bf16(const void* base, int* sh) {
    int t = threadIdx.x;
    if (t == 0) { sh[0] = 0; sh[1] = 0; }
    __syncthreads();
    if (t < 128) {
        ushort4 v = ((const ushort4*)base)[t];
        int nz = (v.x != 0) + (v.y != 0) + (v.z != 0) + (v.w != 0);
        int fp = ((sane16(v.y) && (v.x == 0 || !sane16(v.x))) ? 1 : 0)
               + ((sane16(v.w) && (v.z == 0 || !sane16(v.z))) ? 1 : 0);
        if (nz) atomicAdd(&sh[1], nz);
        if (fp) atomicAdd(&sh[0], fp);
    }
    __syncthreads();
    int fpcnt = sh[0], nzcnt = sh[1];
    if (nzcnt == 0) return 1;
    return (fpcnt < 128) ? 1 : 0;
}
__device__ __forceinline__ float ld_in(const void* base, long idx, int isbf) {
    return isbf ? b2f(((const u16*)base)[idx]) : ((const float*)base)[idx];
}

// ---------------------------------------------------------------------------
// Embedding: x[b,s,:] = emb[ids[b,s],:] + pos[s,:]
// ---------------------------------------------------------------------------
__global__ __launch_bounds__(256) void k_embed(const int* __restrict__ ids,
                                               const void* __restrict__ emb,
                                               const void* __restrict__ pos,
                                               float* __restrict__ x) {
    __shared__ int psh[4];
    int ef = probe_bf16(emb, &psh[0]);
    int pf = probe_bf16(pos, &psh[2]);
    int row = blockIdx.x;
    int s   = row & (Sv - 1);
    long eb = (long)ids[row] * Hv;
    long pb = (long)s * Hv;
    float* o = x + (size_t)row * Hv;
    for (int h = threadIdx.x; h < Hv; h += 256)
        o[h] = ld_in(emb, eb + h, ef) + ld_in(pos, pb + h, pf);
}

// ---------------------------------------------------------------------------
// Split fp32 quad into (hi, lo) bf16 quads. hi = RTZ-truncation (top 16 bits),
// lo = exact residual truncated to bf16. Rel error per elem ~2^-14.
// ---------------------------------------------------------------------------
__device__ __forceinline__ void split4(float4 v, ushort4& h, ushort4& l) {
    unsigned int b, hb;
    b = __builtin_bit_cast(unsigned int, v.x); hb = b & 0xFFFF0000u;
    h.x = (u16)(hb >> 16);
    l.x = (u16)(__builtin_bit_cast(unsigned int, v.x - __builtin_bit_cast(float, hb)) >> 16);
    b = __builtin_bit_cast(unsigned int, v.y); hb = b & 0xFFFF0000u;
    h.y = (u16)(hb >> 16);
    l.y = (u16)(__builtin_bit_cast(unsigned int, v.y - __builtin_bit_cast(float, hb)) >> 16);
    b = __builtin_bit_cast(unsigned int, v.z); hb = b & 0xFFFF0000u;
    h.z = (u16)(hb >> 16);
    l.z = (u16)(__builtin_bit_cast(unsigned int, v.z - __builtin_bit_cast(float, hb)) >> 16);
    b = __builtin_bit_cast(unsigned int, v.w); hb = b & 0xFFFF0000u;
    h.w = (u16)(hb >> 16);
    l.w = (u16)(__builtin_bit_cast(unsigned int, v.w - __builtin_bit_cast(float, hb)) >> 16);
}

__device__ __forceinline__ f32x4 mfma16(u16x8 a, u16x8 b, f32x4 c) {
    return __builtin_amdgcn_mfma_f32_16x16x32_bf16(
        __builtin_bit_cast(bf16x8, a), __builtin_bit_cast(bf16x8, b), c, 0, 0, 0);
}

// ---------------------------------------------------------------------------
// MFMA split-bf16 GEMM: C[M,N] = A[M,K] @ W[N,K]^T (+bias) (+GELU if epi==1)
// A fp32 scratch. W/bias input tensors (probed). bf16 W -> 2-pass
// (A_hi*W + A_lo*W); fp32 W -> 3-pass (+ A_hi*W_lo).
// Tile 128x128, BK=32, 256 thr = 2x2 waves of 64x64 (4x4 frags of 16x16x32).
// Padded LDS rows (LDW=40 u16), no swizzle. M%128==0, N%128==0, K%32==0.
// ---------------------------------------------------------------------------
__global__ __launch_bounds__(256) void k_gemm_mfma(
    const float* __restrict__ A,
    const void* __restrict__ Wb, long Woff,
    const void* __restrict__ Bb, long Boff, int has_bias,
    float* __restrict__ C, int M, int N, int K, int epi, int to_out)
{
    __shared__ __align__(16) u16 Ah[128*LDW];
    __shared__ __align__(16) u16 Al[128*LDW];
    __shared__ __align__(16) u16 Wh[128*LDW];
    __shared__ __align__(16) u16 Wl[128*LDW];
    __shared__ int psh[4];
    const int wf  = probe_bf16(Wb, &psh[0]);
    const int bfl = has_bias ? probe_bf16(Bb, &psh[2]) : 0;

    const int bm = blockIdx.y * 128, bn = blockIdx.x * 128;
    const int tid  = threadIdx.x;
    const int lane = tid & 63, wid = tid >> 6;
    const int wm = (wid >> 1) * 64, wn = (wid & 1) * 64;
    const int fr = lane & 15, fc = lane >> 4;

    // staging: each thread owns rows r0 (0..63) and r1 (64..127), chunk c0 (8 u16)
    const int r0 = tid >> 2, r1 = 64 + (tid >> 2), c0 = tid & 3;
    const size_t arow0 = (size_t)(bm + r0) * K;
    const size_t arow1 = (size_t)(bm + r1) * K;
    const size_t wrow0 = (size_t)Woff + (size_t)(bn + r0) * K;
    const size_t wrow1 = (size_t)Woff + (size_t)(bn + r1) * K;

    f32x4 acc[4][4];
#pragma unroll
    for (int i = 0; i < 4; ++i)
#pragma unroll
        for (int j = 0; j < 4; ++j) acc[i][j] = (f32x4){0.f, 0.f, 0.f, 0.f};

    for (int k0 = 0; k0 < K; k0 += 32) {
        const int kk = k0 + c0 * 8;
        // ---- global -> regs ----
        float4 a0a = *(const float4*)(A + arow0 + kk);
        float4 a0b = *(const float4*)(A + arow0 + kk + 4);
        float4 a1a = *(const float4*)(A + arow1 + kk);
        float4 a1b = *(const float4*)(A + arow1 + kk + 4);
        ushort4 ah0a, al0a, ah0b, al0b, ah1a, al1a, ah1b, al1b;
        split4(a0a, ah0a, al0a); split4(a0b, ah0b, al0b);
        split4(a1a, ah1a, al1a); split4(a1b, ah1b, al1b);

        ushort4 wh0a = {0,0,0,0}, wh0b = {0,0,0,0}, wh1a = {0,0,0,0}, wh1b = {0,0,0,0};
        ushort4 wl0a = {0,0,0,0}, wl0b = {0,0,0,0}, wl1a = {0,0,0,0}, wl1b = {0,0,0,0};
        if (wf) {
            const u16* p0 = (const u16*)Wb + wrow0 + kk;
            const u16* p1 = (const u16*)Wb + wrow1 + kk;
            wh0a = *(const ushort4*)(p0); wh0b = *(const ushort4*)(p0 + 4);
            wh1a = *(const ushort4*)(p1); wh1b = *(const ushort4*)(p1 + 4);
        } else {
            const float* p0 = (const float*)Wb + wrow0 + kk;
            const float* p1 = (const float*)Wb + wrow1 + kk;
            float4 w0a = *(const float4*)(p0); float4 w0b = *(const float4*)(p0 + 4);
            float4 w1a = *(const float4*)(p1); float4 w1b = *(const float4*)(p1 + 4);
            split4(w0a, wh0a, wl0a); split4(w0b, wh0b, wl0b);
            split4(w1a, wh1a, wl1a); split4(w1b, wh1b, wl1b);
        }

        __syncthreads();                       // prev-tile readers done
        const int o0 = r0 * LDW + c0 * 8;
        const int o1 = r1 * LDW + c0 * 8;
        *(ushort4*)&Ah[o0] = ah0a;  *(ushort4*)&Ah[o0 + 4] = ah0b;
        *(ushort4*)&Al[o0] = al0a;  *(ushort4*)&Al[o0 + 4] = al0b;
        *(ushort4*)&Ah[o1] = ah1a;  *(ushort4*)&Ah[o1 + 4] = ah1b;
        *(ushort4*)&Al[o1] = al1a;  *(ushort4*)&Al[o1 + 4] = al1b;
        *(ushort4*)&Wh[o0] = wh0a;  *(ushort4*)&Wh[o0 + 4] = wh0b;
        *(ushort4*)&Wh[o1] = wh1a;  *(ushort4*)&Wh[o1 + 4] = wh1b;
        if (!wf) {
            *(ushort4*)&Wl[o0] = wl0a;  *(ushort4*)&Wl[o0 + 4] = wl0b;
            *(ushort4*)&Wl[o1] = wl1a;  *(ushort4*)&Wl[o1 + 4] = wl1b;
        }
        __syncthreads();

        // ---- fragments: lane holds row (base+fr), k-chunk fc (8 contiguous) ----
        u16x8 af[4], alf[4], wfh[4], wfl[4];
#pragma unroll
        for (int mi = 0; mi < 4; ++mi) {
            const int r = wm + mi * 16 + fr;
            af[mi]  = *(const u16x8*)&Ah[r * LDW + fc * 8];
            alf[mi] = *(const u16x8*)&Al[r * LDW + fc * 8];
        }
#pragma unroll
        for (int ni = 0; ni < 4; ++ni) {
            const int r = wn + ni * 16 + fr;
            wfh[ni] = *(const u16x8*)&Wh[r * LDW + fc * 8];
            if (!wf) wfl[ni] = *(const u16x8*)&Wl[r * LDW + fc * 8];
        }
        // ---- 2 or 3 MFMA passes into the same fp32 acc ----
#pragma unroll
        for (int mi = 0; mi < 4; ++mi)
#pragma unroll
            for (int ni = 0; ni < 4; ++ni) {
                acc[mi][ni] = mfma16(af[mi],  wfh[ni], acc[mi][ni]);
                acc[mi][ni] = mfma16(alf[mi], wfh[ni], acc[mi][ni]);
            }
        if (!wf) {
#pragma unroll
            for (int mi = 0; mi < 4; ++mi)
#pragma unroll
                for (int ni = 0; ni < 4; ++ni)
                    acc[mi][ni] = mfma16(af[mi], wfl[ni], acc[mi][ni]);
        }
    }

    // ---- epilogue: C/D layout col=lane&15, row=(lane>>4)*4+reg (m89) ----
#pragma unroll
    for (int ni = 0; ni < 4; ++ni) {
        const int col = bn + wn + ni * 16 + fr;
        const float bias = has_bias ? ld_in(Bb, Boff + col, bfl) : 0.f;
#pragma unroll
        for (int mi = 0; mi < 4; ++mi) {
#pragma unroll
            for (int r = 0; r < 4; ++r) {
                const int row = bm + wm + mi * 16 + fc * 4 + r;
                float v = acc[mi][ni][r] + bias;
                if (epi == 1) v = 0.5f * v * (1.f + erff(v * 0.70710678118654752f));
                size_t idx = (size_t)row * N + col;
                if (to_out && wf) ((u16*)C)[idx] = f2b(v);
                else              C[idx] = v;
            }
        }
    }
}

// ---------------------------------------------------------------------------
// u = sigmoid(gpre) * ub
// ---------------------------------------------------------------------------
__global__ __launch_bounds__(256) void k_gate(const float* __restrict__ gpre,
                                              const float* __restrict__ ub,
                                              float* __restrict__ u, int n) {
    int i = blockIdx.x * 256 + threadIdx.x;
    if (i < n) {
        float s = 1.f / (1.f + expf(-gpre[i]));
        u[i] = s * ub[i];
    }
}

// ---------------------------------------------------------------------------
// Selective-scan: st[b,s,n] = A[n]*st[b,s-1,n] + u[b,s,n],  A = exp(A_log)
// ---------------------------------------------------------------------------
__global__ __launch_bounds__(128) void k_scan(const void* __restrict__ A_log, long off,
                                              const float* __restrict__ u,
                                              float* __restrict__ st) {
    __shared__ int psh[2];
    int af = probe_bf16(A_log, psh);
    int b = blockIdx.x, n = threadIdx.x;
    float A = expf(ld_in(A_log, off + n, af));
    const float* up = u  + (size_t)b * Sv * Nv + n;
    float*       sp = st + (size_t)b * Sv * Nv + n;
    float s = 0.f;
    for (int t = 0; t < Sv; ++t) {
        s = fmaf(A, s, up[(size_t)t * Nv]);
        sp[(size_t)t * Nv] = s;
    }
}

// ---------------------------------------------------------------------------
// y += (Dp[h]+1) * x
// ---------------------------------------------------------------------------
__global__ __launch_bounds__(256) void k_dx(float* __restrict__ y,
                                            const float* __restrict__ x,
                                            const void* __restrict__ Dp, long off) {
    __shared__ int psh[2];
    int df = probe_bf16(Dp, psh);
    int row = blockIdx.x;
    size_t base = (size_t)row * Hv;
    for (int h = threadIdx.x; h < Hv; h += 256)
        y[base + h] = fmaf(ld_in(Dp, off + h, df) + 1.f, x[base + h], y[base + h]);
}

// ---------------------------------------------------------------------------
// LayerNorm: out = postscale * ( LN(a (+ b)) * g + beta ), H=1024, eps=1e-5.
// ---------------------------------------------------------------------------
__global__ __launch_bounds__(256) void k_ln(const float* __restrict__ a,
                                            const float* __restrict__ b,
                                            const void* __restrict__ g, long goff,
                                            const void* __restrict__ bb, long boff,
                                            float* __restrict__ out,
                                            float postscale) {
    __shared__ float buf[Hv];
    __shared__ float red[4];
    __shared__ int psh[4];
    int gf_ = probe_bf16(g, &psh[0]);
    int bf_ = probe_bf16(bb, &psh[2]);
    int row = blockIdx.x, t = threadIdx.x;
    const float* ap = a + (size_t)row * Hv;
    const float* bp = b ? b + (size_t)row * Hv : nullptr;
    float ls = 0.f;
    for (int h = t; h < Hv; h += 256) {
        float v = ap[h] + (bp ? bp[h] : 0.f);
        buf[h] = v; ls += v;
    }
#pragma unroll
    for (int o = 32; o > 0; o >>= 1) ls += __shfl_down(ls, o, 64);
    if ((t & 63) == 0) red[t >> 6] = ls;
    __syncthreads();
    float mu = (red[0] + red[1] + red[2] + red[3]) * (1.f / Hv);
    __syncthreads();
    float lv = 0.f;
    for (int h = t; h < Hv; h += 256) { float d = buf[h] - mu; lv += d * d; }
#pragma unroll
    for (int o = 32; o > 0; o >>= 1) lv += __shfl_down(lv, o, 64);
    if ((t & 63) == 0) red[t >> 6] = lv;
    __syncthreads();
    float rstd = rsqrtf((red[0] + red[1] + red[2] + red[3]) * (1.f / Hv) + 1e-5f);
    for (int h = t; h < Hv; h += 256)
        out[(size_t)row * Hv + h] =
            ((buf[h] - mu) * rstd * ld_in(g, goff + h, gf_) + ld_in(bb, boff + h, bf_)) * postscale;
}

// ---------------------------------------------------------------------------
// Fused attention: one block per (b, head, q-row), 128 threads.
// ---------------------------------------------------------------------------
__global__ __launch_bounds__(128) void k_attn(const float* __restrict__ qkv,
                                              float* __restrict__ ao) {
    __shared__ float qs[DHv];
    __shared__ float att[Sv];
    __shared__ float redm[2], reds[2];
    int q = blockIdx.x, h = blockIdx.y, b = blockIdx.z;
    int t = threadIdx.x;
    const size_t rs = 3 * (size_t)Hv;
    const float* qp = qkv + ((size_t)b * Sv + q) * rs + h * DHv;
    const float* kp = qkv + (size_t)b * Sv * rs + Hv     + h * DHv;
    const float* vp = qkv + (size_t)b * Sv * rs + 2 * Hv + h * DHv;

    qs[t] = qp[t] * 0.08838834764831845f;   // 1/sqrt(128)
    __syncthreads();

    float lmax = -1e30f;
    for (int k = t; k < Sv; k += 128) {
        const float4* kr = (const float4*)(kp + (size_t)k * rs);
        const float4* q4 = (const float4*)qs;
        float d = 0.f;
#pragma unroll
        for (int j = 0; j < DHv / 4; ++j) {
            float4 kv = kr[j], qv = q4[j];
            d += qv.x * kv.x + qv.y * kv.y + qv.z * kv.z + qv.w * kv.w;
        }
        att[k] = d;
        lmax = fmaxf(lmax, d);
    }
#pragma unroll
    for (int o = 32; o > 0; o >>= 1) lmax = fmaxf(lmax, __shfl_down(lmax, o, 64));
    if ((t & 63) == 0) redm[t >> 6] = lmax;
    __syncthreads();
    float m = fmaxf(redm[0], redm[1]);

    float lsum = 0.f;
    for (int k = t; k < Sv; k += 128) {
        float e = expf(att[k] - m);
        att[k] = e; lsum += e;
    }
#pragma unroll
    for (int o = 32; o > 0; o >>= 1) lsum += __shfl_down(lsum, o, 64);
    if ((t & 63) == 0) reds[t >> 6] = lsum;
    __syncthreads();
    float inv = 1.f / (reds[0] + reds[1]);

    float o = 0.f;
    for (int k = 0; k < Sv; ++k)
        o = fmaf(att[k], vp[(size_t)k * rs + t], o);
    ao[((size_t)b * Sv + q) * Hv + h * DHv + t] = o * inv;
}

// ---------------------------------------------------------------------------
extern "C" void kernel_launch(void* const* d_in, const int* in_sizes, int n_in,
                              void* d_out, int out_size, void* d_ws, size_t ws_size,
                              hipStream_t stream) {
    const int*  ids   = (const int*)d_in[0];
    const void *emb = d_in[1], *pos = d_in[2], *A_log = d_in[3], *WB = d_in[4],
               *WC = d_in[5], *Dp = d_in[6], *Wg = d_in[7], *bg = d_in[8],
               *Wout = d_in[9], *bout = d_in[10], *gs = d_in[11], *bs = d_in[12],
               *Wqkv = d_in[13], *bqkv = d_in[14], *Wo = d_in[15], *bo = d_in[16],
               *W1 = d_in[17], *b1 = d_in[18], *W2 = d_in[19], *b2 = d_in[20],
               *g1 = d_in[21], *bn1 = d_in[22], *g2 = d_in[23], *bn2 = d_in[24],
               *g3 = d_in[25], *bn3 = d_in[26], *gf = d_in[27], *bf = d_in[28];

    // Scratch: front 56 MB of d_out (dead before the final GEMM overwrites all
    // of d_out). FINAL (read while d_out is written) lives in d_ws (8 MB).
    char* ob = (char*)d_out;
    float* X   = (float*)(ob + 0);          //  8 MB  [2048,1024]
    float* T1  = (float*)(ob + 8388608);    //  8 MB  [2048,1024]
    float* T2  = (float*)(ob + 16777216);   //  8 MB  [2048,1024]
    float* FH  = (float*)(ob + 25165824);   // 32 MB  [2048,4096]
    float* QKV = FH;                        // 24 MB  [2048,3072]  (aliased)
    float* G   = FH;                        //  1 MB  [2048,128]   (aliased)
    float* U   = (float*)(ob + 25165824 + 1048576);
    float* ST  = (float*)(ob + 25165824 + 2097152);
    float* FINAL = (float*)d_ws;            //  8 MB  [2048,1024]

    auto gemm = [&](const float* A, const void* W, long Woff, const void* bias, long Boff,
                    int hasb, float* C, int M, int N, int K, int epi, int to_out) {
        dim3 grid(N / 128, M / 128);
        k_gemm_mfma<<<grid, 256, 0, stream>>>(A, W, Woff, bias, Boff, hasb, C, M, N, K, epi, to_out);
    };

    k_embed<<<Mv, 256, 0, stream>>>(ids, emb, pos, X);

    for (int i = 0; i < Lv; ++i) {
        long oNH = (long)i * Nv * Hv, oHN = (long)i * Hv * Nv, oHH = (long)i * Hv * Hv;
        long oN = (long)i * Nv, oH = (long)i * Hv;

        // --- SSM block ---
        gemm(X, Wg, oNH, bg, oN, 1, G, Mv, Nv, Hv, 0, 0);           // gate pre-act
        gemm(X, WB, oNH, nullptr, 0, 0, U, Mv, Nv, Hv, 0, 0);       // B proj
        k_gate<<<(Mv * Nv) / 256, 256, 0, stream>>>(G, U, U, Mv * Nv);
        k_scan<<<Bv, 128, 0, stream>>>(A_log, oN, U, ST);
        gemm(ST, WC, oHN, nullptr, 0, 0, T1, Mv, Hv, Nv, 0, 0);     // y = st @ WC^T
        k_dx<<<Mv, 256, 0, stream>>>(T1, X, Dp, oH);                // += (Dp+1)*x
        k_ln<<<Mv, 256, 0, stream>>>(T1, nullptr, gs, oH, bs, oH, T2, 1.f);
        gemm(T2, Wout, oHH, bout, oH, 1, T1, Mv, Hv, Hv, 0, 0);     // xs
        k_ln<<<Mv, 256, 0, stream>>>(X, T1, g1, oH, bn1, oH, X, 1.f);

        // --- attention (odd layers); HierarchicalMemory x2 folds into LN postscale ---
        if (i & 1) {
            gemm(X, Wqkv, 3 * oHH, bqkv, 3 * oH, 1, QKV, Mv, 3 * Hv, Hv, 0, 0);
            dim3 ag(Sv, NHv, Bv);
            k_attn<<<ag, 128, 0, stream>>>(QKV, T1);
            gemm(T1, Wo, oHH, bo, oH, 1, T2, Mv, Hv, Hv, 0, 0);
            k_ln<<<Mv, 256, 0, stream>>>(X, T2, g2, oH, bn2, oH, X, 2.f);
        } else {
            k_ln<<<Mv, 256, 0, stream>>>(X, nullptr, g2, oH, bn2, oH, X, 2.f);
        }

        // --- FFN ---
        gemm(X, W1, (long)i * FFv * Hv, b1, (long)i * FFv, 1, FH, Mv, FFv, Hv, 1, 0);
        gemm(FH, W2, (long)i * Hv * FFv, b2, oH, 1, T1, Mv, Hv, FFv, 0, 0);
        k_ln<<<Mv, 256, 0, stream>>>(X, T1, g3, oH, bn3, oH, X, 1.f);
    }

    // --- final LN (into d_ws) + tied lm_head (dtype follows emb; fills d_out) ---
    k_ln<<<Mv, 256, 0, stream>>>(X, nullptr, gf, 0, bf, 0, FINAL, 1.f);
    gemm(FINAL, emb, 0, nullptr, 0, 0, (float*)d_out, Mv, Vv, Hv, 0, 1);
}

// Round 3
// 5850.441 us; speedup vs baseline: 2.2491x; 1.4736x over previous
//
#include <hip/hip_runtime.h>
#include <math.h>

// Problem dims (fixed)
#define Bv   4
#define Sv   512
#define Hv   1024
#define Nv   128
#define Lv   6
#define Vv   32000
#define NHv  8
#define FFv  4096
#define DHv  128
#define Mv   (Bv*Sv)   // 2048 token rows

typedef unsigned short u16;
typedef __bf16  bf16x8 __attribute__((ext_vector_type(8)));
typedef unsigned short u16x8 __attribute__((ext_vector_type(8)));
typedef float   f32x4  __attribute__((ext_vector_type(4)));

// LDS tile row stride in u16 units: 40 (=80B). Rows stay 16B-aligned
// (40*2=80, 80%16==0); fragment reads at stride 80B hit banks
// (20*r+4*c)%32 -> 8 distinct banks x 2 lanes = 2-way = free (m136).
#define LDW 40

// bf16 (as ushort) <-> fp32
__device__ __forceinline__ float b2f(u16 u) {
    union { unsigned int i; float f; } v; v.i = ((unsigned int)u) << 16; return v.f;
}
__device__ __forceinline__ u16 f2b(float f) {
    union { float f; unsigned int i; } v; v.f = f;
    unsigned int x = v.i;
    return (u16)((x + 0x7fffu + ((x >> 16) & 1u)) >> 16);   // RNE
}

// ---------------------------------------------------------------------------
// On-device dtype probe. Requires blockDim >= 128. Returns 1 if bf16.
// ---------------------------------------------------------------------------
__device__ __forceinline__ int sane16(u16 u) {
    if (u == 0) return 1;
    int e = (u >> 7) & 0xFF;
    return (e >= 0x66 && e <= 0x8F);
}
__device__ __forceinline__ int probe_bf16(const void* base, int* sh) {
    int t = threadIdx.x;
    if (t == 0) { sh[0] = 0; sh[1] = 0; }
    __syncthreads();
    if (t < 128) {
        ushort4 v = ((const ushort4*)base)[t];
        int nz = (v.x != 0) + (v.y != 0) + (v.z != 0) + (v.w != 0);
        int fp = ((sane16(v.y) && (v.x == 0 || !sane16(v.x))) ? 1 : 0)
               + ((sane16(v.w) && (v.z == 0 || !sane16(v.z))) ? 1 : 0);
        if (nz) atomicAdd(&sh[1], nz);
        if (fp) atomicAdd(&sh[0], fp);
    }
    __syncthreads();
    int fpcnt = sh[0], nzcnt = sh[1];
    if (nzcnt == 0) return 1;
    return (fpcnt < 128) ? 1 : 0;
}
__device__ __forceinline__ float ld_in(const void* base, long idx, int isbf) {
    return isbf ? b2f(((const u16*)base)[idx]) : ((const float*)base)[idx];
}

// ---------------------------------------------------------------------------
// Embedding: x[b,s,:] = emb[ids[b,s],:] + pos[s,:]
// ---------------------------------------------------------------------------
__global__ __launch_bounds__(256) void k_embed(const int* __restrict__ ids,
                                               const void* __restrict__ emb,
                                               const void* __restrict__ pos,
                                               float* __restrict__ x) {
    __shared__ int psh[4];
    int ef = probe_bf16(emb, &psh[0]);
    int pf = probe_bf16(pos, &psh[2]);
    int row = blockIdx.x;
    int s   = row & (Sv - 1);
    long eb = (long)ids[row] * Hv;
    long pb = (long)s * Hv;
    float* o = x + (size_t)row * Hv;
    for (int h = threadIdx.x; h < Hv; h += 256)
        o[h] = ld_in(emb, eb + h, ef) + ld_in(pos, pb + h, pf);
}

// ---------------------------------------------------------------------------
// fp32x4 -> bf16x4 RNE via compiler conversion (emits v_cvt_pk_bf16_f32).
// ---------------------------------------------------------------------------
__device__ __forceinline__ ushort4 cvt4(float4 v) {
    ushort4 r;
    r.x = __builtin_bit_cast(u16, (__bf16)v.x);
    r.y = __builtin_bit_cast(u16, (__bf16)v.y);
    r.z = __builtin_bit_cast(u16, (__bf16)v.z);
    r.w = __builtin_bit_cast(u16, (__bf16)v.w);
    return r;
}

__device__ __forceinline__ f32x4 mfma16(u16x8 a, u16x8 b, f32x4 c) {
    return __builtin_amdgcn_mfma_f32_16x16x32_bf16(
        __builtin_bit_cast(bf16x8, a), __builtin_bit_cast(bf16x8, b), c, 0, 0, 0);
}

// ---------------------------------------------------------------------------
// Single-pass bf16 MFMA GEMM: C[M,N] = A[M,K] @ W[N,K]^T (+bias)(+GELU epi).
// A fp32 scratch (RNE->bf16 at staging). W input tensor: bf16 loaded direct,
// fp32 RNE-converted at staging. Accuracy: ~1.6e-3 relative per GEMM.
// Tile BM x BN (templated), BK=32, 256 thr = 2x2 waves, 16x16x32 frags.
// Padded LDS rows (LDW=40 u16). Requires M%BM==0, N%BN==0, K%32==0.
// ---------------------------------------------------------------------------
template<int BM, int BN>
__global__ __launch_bounds__(256) void k_gemm_t(
    const float* __restrict__ A,
    const void* __restrict__ Wb, long Woff,
    const void* __restrict__ Bb, long Boff, int has_bias,
    float* __restrict__ C, int M, int N, int K, int epi, int to_out)
{
    constexpr int FM = BM / 32, FN = BN / 32;   // 16x16 frags per wave (M,N)
    constexpr int NA = BM / 64, NW = BN / 64;   // staged row-iters per thread
    __shared__ __align__(16) u16 Ah[BM * LDW];
    __shared__ __align__(16) u16 Wh[BN * LDW];
    __shared__ int psh[4];
    const int wf  = probe_bf16(Wb, &psh[0]);
    const int bfl = has_bias ? probe_bf16(Bb, &psh[2]) : 0;

    const int bm = blockIdx.y * BM, bn = blockIdx.x * BN;
    const int tid  = threadIdx.x;
    const int lane = tid & 63, wid = tid >> 6;
    const int wm = (wid >> 1) * (BM / 2), wn = (wid & 1) * (BN / 2);
    const int fr = lane & 15, fc = lane >> 4;
    const int r0 = tid >> 2, c0 = tid & 3;      // staging row / 8-elem chunk

    f32x4 acc[FM][FN];
#pragma unroll
    for (int i = 0; i < FM; ++i)
#pragma unroll
        for (int j = 0; j < FN; ++j) acc[i][j] = (f32x4){0.f, 0.f, 0.f, 0.f};

    for (int k0 = 0; k0 < K; k0 += 32) {
        const int kk = k0 + c0 * 8;
        // ---- global -> regs, convert to bf16 (RNE) ----
        ushort4 as[NA][2], ws[NW][2];
#pragma unroll
        for (int ia = 0; ia < NA; ++ia) {
            const float* p = A + (size_t)(bm + r0 + 64 * ia) * K + kk;
            as[ia][0] = cvt4(*(const float4*)p);
            as[ia][1] = cvt4(*(const float4*)(p + 4));
        }
#pragma unroll
        for (int iw = 0; iw < NW; ++iw) {
            const size_t wrow = (size_t)Woff + (size_t)(bn + r0 + 64 * iw) * K + kk;
            if (wf) {
                const u16* p = (const u16*)Wb + wrow;
                ws[iw][0] = *(const ushort4*)p;
                ws[iw][1] = *(const ushort4*)(p + 4);
            } else {
                const float* p = (const float*)Wb + wrow;
                ws[iw][0] = cvt4(*(const float4*)p);
                ws[iw][1] = cvt4(*(const float4*)(p + 4));
            }
        }

        __syncthreads();                       // prev-tile readers done
#pragma unroll
        for (int ia = 0; ia < NA; ++ia) {
            const int o = (r0 + 64 * ia) * LDW + c0 * 8;
            *(ushort4*)&Ah[o]     = as[ia][0];
            *(ushort4*)&Ah[o + 4] = as[ia][1];
        }
#pragma unroll
        for (int iw = 0; iw < NW; ++iw) {
            const int o = (r0 + 64 * iw) * LDW + c0 * 8;
            *(ushort4*)&Wh[o]     = ws[iw][0];
            *(ushort4*)&Wh[o + 4] = ws[iw][1];
        }
        __syncthreads();

        // ---- fragments: lane = row (base+fr), k-chunk fc (8 contiguous) ----
        u16x8 af[FM], wfr[FN];
#pragma unroll
        for (int mi = 0; mi < FM; ++mi)
            af[mi] = *(const u16x8*)&Ah[(wm + mi * 16 + fr) * LDW + fc * 8];
#pragma unroll
        for (int ni = 0; ni < FN; ++ni)
            wfr[ni] = *(const u16x8*)&Wh[(wn + ni * 16 + fr) * LDW + fc * 8];

#pragma unroll
        for (int mi = 0; mi < FM; ++mi)
#pragma unroll
            for (int ni = 0; ni < FN; ++ni)
                acc[mi][ni] = mfma16(af[mi], wfr[ni], acc[mi][ni]);
    }

    // ---- epilogue: C/D layout col=lane&15, row=(lane>>4)*4+reg (m89) ----
#pragma unroll
    for (int ni = 0; ni < FN; ++ni) {
        const int col = bn + wn + ni * 16 + fr;
        const float bias = has_bias ? ld_in(Bb, Boff + col, bfl) : 0.f;
#pragma unroll
        for (int mi = 0; mi < FM; ++mi) {
#pragma unroll
            for (int r = 0; r < 4; ++r) {
                const int row = bm + wm + mi * 16 + fc * 4 + r;
                float v = acc[mi][ni][r] + bias;
                if (epi == 1) v = 0.5f * v * (1.f + erff(v * 0.70710678118654752f));
                size_t idx = (size_t)row * N + col;
                if (to_out && wf) ((u16*)C)[idx] = f2b(v);
                else              C[idx] = v;
            }
        }
    }
}

// ---------------------------------------------------------------------------
// u = sigmoid(gpre) * ub
// ---------------------------------------------------------------------------
__global__ __launch_bounds__(256) void k_gate(const float* __restrict__ gpre,
                                              const float* __restrict__ ub,
                                              float* __restrict__ u, int n) {
    int i = blockIdx.x * 256 + threadIdx.x;
    if (i < n) {
        float s = 1.f / (1.f + expf(-gpre[i]));
        u[i] = s * ub[i];
    }
}

// ---------------------------------------------------------------------------
// Selective-scan: st[b,s,n] = A[n]*st[b,s-1,n] + u[b,s,n],  A = exp(A_log)
// ---------------------------------------------------------------------------
__global__ __launch_bounds__(128) void k_scan(const void* __restrict__ A_log, long off,
                                              const float* __restrict__ u,
                                              float* __restrict__ st) {
    __shared__ int psh[2];
    int af = probe_bf16(A_log, psh);
    int b = blockIdx.x, n = threadIdx.x;
    float A = expf(ld_in(A_log, off + n, af));
    const float* up = u  + (size_t)b * Sv * Nv + n;
    float*       sp = st + (size_t)b * Sv * Nv + n;
    float s = 0.f;
    for (int t = 0; t < Sv; ++t) {
        s = fmaf(A, s, up[(size_t)t * Nv]);
        sp[(size_t)t * Nv] = s;
    }
}

// ---------------------------------------------------------------------------
// y += (Dp[h]+1) * x
// ---------------------------------------------------------------------------
__global__ __launch_bounds__(256) void k_dx(float* __restrict__ y,
                                            const float* __restrict__ x,
                                            const void* __restrict__ Dp, long off) {
    __shared__ int psh[2];
    int df = probe_bf16(Dp, psh);
    int row = blockIdx.x;
    size_t base = (size_t)row * Hv;
    for (int h = threadIdx.x; h < Hv; h += 256)
        y[base + h] = fmaf(ld_in(Dp, off + h, df) + 1.f, x[base + h], y[base + h]);
}

// ---------------------------------------------------------------------------
// LayerNorm: out = postscale * ( LN(a (+ b)) * g + beta ), H=1024, eps=1e-5.
// ---------------------------------------------------------------------------
__global__ __launch_bounds__(256) void k_ln(const float* __restrict__ a,
                                            const float* __restrict__ b,
                                            const void* __restrict__ g, long goff,
                                            const void* __restrict__ bb, long boff,
                                            float* __restrict__ out,
                                            float postscale) {
    __shared__ float buf[Hv];
    __shared__ float red[4];
    __shared__ int psh[4];
    int gf_ = probe_bf16(g, &psh[0]);
    int bf_ = probe_bf16(bb, &psh[2]);
    int row = blockIdx.x, t = threadIdx.x;
    const float* ap = a + (size_t)row * Hv;
    const float* bp = b ? b + (size_t)row * Hv : nullptr;
    float ls = 0.f;
    for (int h = t; h < Hv; h += 256) {
        float v = ap[h] + (bp ? bp[h] : 0.f);
        buf[h] = v; ls += v;
    }
#pragma unroll
    for (int o = 32; o > 0; o >>= 1) ls += __shfl_down(ls, o, 64);
    if ((t & 63) == 0) red[t >> 6] = ls;
    __syncthreads();
    float mu = (red[0] + red[1] + red[2] + red[3]) * (1.f / Hv);
    __syncthreads();
    float lv = 0.f;
    for (int h = t; h < Hv; h += 256) { float d = buf[h] - mu; lv += d * d; }
#pragma unroll
    for (int o = 32; o > 0; o >>= 1) lv += __shfl_down(lv, o, 64);
    if ((t & 63) == 0) red[t >> 6] = lv;
    __syncthreads();
    float rstd = rsqrtf((red[0] + red[1] + red[2] + red[3]) * (1.f / Hv) + 1e-5f);
    for (int h = t; h < Hv; h += 256)
        out[(size_t)row * Hv + h] =
            ((buf[h] - mu) * rstd * ld_in(g, goff + h, gf_) + ld_in(bb, boff + h, bf_)) * postscale;
}

// ---------------------------------------------------------------------------
// Fused attention: one block per (b, head, q-row), 128 threads.
// ---------------------------------------------------------------------------
__global__ __launch_bounds__(128) void k_attn(const float* __restrict__ qkv,
                                              float* __restrict__ ao) {
    __shared__ float qs[DHv];
    __shared__ float att[Sv];
    __shared__ float redm[2], reds[2];
    int q = blockIdx.x, h = blockIdx.y, b = blockIdx.z;
    int t = threadIdx.x;
    const size_t rs = 3 * (size_t)Hv;
    const float* qp = qkv + ((size_t)b * Sv + q) * rs + h * DHv;
    const float* kp = qkv + (size_t)b * Sv * rs + Hv     + h * DHv;
    const float* vp = qkv + (size_t)b * Sv * rs + 2 * Hv + h * DHv;

    qs[t] = qp[t] * 0.08838834764831845f;   // 1/sqrt(128)
    __syncthreads();

    float lmax = -1e30f;
    for (int k = t; k < Sv; k += 128) {
        const float4* kr = (const float4*)(kp + (size_t)k * rs);
        const float4* q4 = (const float4*)qs;
        float d = 0.f;
#pragma unroll
        for (int j = 0; j < DHv / 4; ++j) {
            float4 kv = kr[j], qv = q4[j];
            d += qv.x * kv.x + qv.y * kv.y + qv.z * kv.z + qv.w * kv.w;
        }
        att[k] = d;
        lmax = fmaxf(lmax, d);
    }
#pragma unroll
    for (int o = 32; o > 0; o >>= 1) lmax = fmaxf(lmax, __shfl_down(lmax, o, 64));
    if ((t & 63) == 0) redm[t >> 6] = lmax;
    __syncthreads();
    float m = fmaxf(redm[0], redm[1]);

    float lsum = 0.f;
    for (int k = t; k < Sv; k += 128) {
        float e = expf(att[k] - m);
        att[k] = e; lsum += e;
    }
#pragma unroll
    for (int o = 32; o > 0; o >>= 1) lsum += __shfl_down(lsum, o, 64);
    if ((t & 63) == 0) reds[t >> 6] = lsum;
    __syncthreads();
    float inv = 1.f / (reds[0] + reds[1]);

    float o = 0.f;
    for (int k = 0; k < Sv; ++k)
        o = fmaf(att[k], vp[(size_t)k * rs + t], o);
    ao[((size_t)b * Sv + q) * Hv + h * DHv + t] = o * inv;
}

// ---------------------------------------------------------------------------
extern "C" void kernel_launch(void* const* d_in, const int* in_sizes, int n_in,
                              void* d_out, int out_size, void* d_ws, size_t ws_size,
                              hipStream_t stream) {
    const int*  ids   = (const int*)d_in[0];
    const void *emb = d_in[1], *pos = d_in[2], *A_log = d_in[3], *WB = d_in[4],
               *WC = d_in[5], *Dp = d_in[6], *Wg = d_in[7], *bg = d_in[8],
               *Wout = d_in[9], *bout = d_in[10], *gs = d_in[11], *bs = d_in[12],
               *Wqkv = d_in[13], *bqkv = d_in[14], *Wo = d_in[15], *bo = d_in[16],
               *W1 = d_in[17], *b1 = d_in[18], *W2 = d_in[19], *b2 = d_in[20],
               *g1 = d_in[21], *bn1 = d_in[22], *g2 = d_in[23], *bn2 = d_in[24],
               *g3 = d_in[25], *bn3 = d_in[26], *gf = d_in[27], *bf = d_in[28];

    // Scratch: front 56 MB of d_out (dead before the final GEMM overwrites all
    // of d_out). FINAL (read while d_out is written) lives in d_ws (8 MB).
    char* ob = (char*)d_out;
    float* X   = (float*)(ob + 0);          //  8 MB  [2048,1024]
    float* T1  = (float*)(ob + 8388608);    //  8 MB  [2048,1024]
    float* T2  = (float*)(ob + 16777216);   //  8 MB  [2048,1024]
    float* FH  = (float*)(ob + 25165824);   // 32 MB  [2048,4096]
    float* QKV = FH;                        // 24 MB  [2048,3072]  (aliased)
    float* G   = FH;                        //  1 MB  [2048,128]   (aliased)
    float* U   = (float*)(ob + 25165824 + 1048576);
    float* ST  = (float*)(ob + 25165824 + 2097152);
    float* FINAL = (float*)d_ws;            //  8 MB  [2048,1024]

    // Tile choice by N: big-N -> 128x128; N=1024 -> 128x64 (grid 256 blocks);
    // N=128 -> 64x64 (grid 64 blocks). All driven by grid-parallelism.
    auto gemm = [&](const float* A, const void* W, long Woff, const void* bias, long Boff,
                    int hasb, float* C, int M, int N, int K, int epi, int to_out) {
        if (N >= 3072) {
            dim3 grid(N / 128, M / 128);
            k_gemm_t<128,128><<<grid, 256, 0, stream>>>(A, W, Woff, bias, Boff, hasb, C, M, N, K, epi, to_out);
        } else if (N >= 1024) {
            dim3 grid(N / 64, M / 128);
            k_gemm_t<128,64><<<grid, 256, 0, stream>>>(A, W, Woff, bias, Boff, hasb, C, M, N, K, epi, to_out);
        } else {
            dim3 grid(N / 64, M / 64);
            k_gemm_t<64,64><<<grid, 256, 0, stream>>>(A, W, Woff, bias, Boff, hasb, C, M, N, K, epi, to_out);
        }
    };

    k_embed<<<Mv, 256, 0, stream>>>(ids, emb, pos, X);

    for (int i = 0; i < Lv; ++i) {
        long oNH = (long)i * Nv * Hv, oHN = (long)i * Hv * Nv, oHH = (long)i * Hv * Hv;
        long oN = (long)i * Nv, oH = (long)i * Hv;

        // --- SSM block ---
        gemm(X, Wg, oNH, bg, oN, 1, G, Mv, Nv, Hv, 0, 0);           // gate pre-act
        gemm(X, WB, oNH, nullptr, 0, 0, U, Mv, Nv, Hv, 0, 0);       // B proj
        k_gate<<<(Mv * Nv) / 256, 256, 0, stream>>>(G, U, U, Mv * Nv);
        k_scan<<<Bv, 128, 0, stream>>>(A_log, oN, U, ST);
        gemm(ST, WC, oHN, nullptr, 0, 0, T1, Mv, Hv, Nv, 0, 0);     // y = st @ WC^T
        k_dx<<<Mv, 256, 0, stream>>>(T1, X, Dp, oH);                // += (Dp+1)*x
        k_ln<<<Mv, 256, 0, stream>>>(T1, nullptr, gs, oH, bs, oH, T2, 1.f);
        gemm(T2, Wout, oHH, bout, oH, 1, T1, Mv, Hv, Hv, 0, 0);     // xs
        k_ln<<<Mv, 256, 0, stream>>>(X, T1, g1, oH, bn1, oH, X, 1.f);

        // --- attention (odd layers); HierarchicalMemory x2 folds into LN postscale ---
        if (i & 1) {
            gemm(X, Wqkv, 3 * oHH, bqkv, 3 * oH, 1, QKV, Mv, 3 * Hv, Hv, 0, 0);
            dim3 ag(Sv, NHv, Bv);
            k_attn<<<ag, 128, 0, stream>>>(QKV, T1);
            gemm(T1, Wo, oHH, bo, oH, 1, T2, Mv, Hv, Hv, 0, 0);
            k_ln<<<Mv, 256, 0, stream>>>(X, T2, g2, oH, bn2, oH, X, 2.f);
        } else {
            k_ln<<<Mv, 256, 0, stream>>>(X, nullptr, g2, oH, bn2, oH, X, 2.f);
        }

        // --- FFN ---
        gemm(X, W1, (long)i * FFv * Hv, b1, (long)i * FFv, 1, FH, Mv, FFv, Hv, 1, 0);
        gemm(FH, W2, (long)i * Hv * FFv, b2, oH, 1, T1, Mv, Hv, FFv, 0, 0);
        k_ln<<<Mv, 256, 0, stream>>>(X, T1, g3, oH, bn3, oH, X, 1.f);
    }

    // --- final LN (into d_ws) + tied lm_head (dtype follows emb; fills d_out) ---
    k_ln<<<Mv, 256, 0, stream>>>(X, nullptr, gf, 0, bf, 0, FINAL, 1.f);
    gemm(FINAL, emb, 0, nullptr, 0, 0, (float*)d_out, Mv, Vv, Hv, 0, 1);
}

// Round 4
// 4296.829 us; speedup vs baseline: 3.0623x; 1.3616x over previous
//
#include <hip/hip_runtime.h>
#include <math.h>

// Problem dims (fixed)
#define Bv   4
#define Sv   512
#define Hv   1024
#define Nv   128
#define Lv   6
#define Vv   32000
#define NHv  8
#define FFv  4096
#define DHv  128
#define Mv   (Bv*Sv)   // 2048 token rows

typedef unsigned short u16;
typedef __bf16  bf16x8 __attribute__((ext_vector_type(8)));
typedef unsigned short u16x8 __attribute__((ext_vector_type(8)));
typedef float   f32x4  __attribute__((ext_vector_type(4)));

// LDS tile row stride in u16 units: 40 (=80B), 16B-aligned rows, ~2-way banks.
#define LDW 40

// bf16 (as ushort) <-> fp32
__device__ __forceinline__ float b2f(u16 u) {
    union { unsigned int i; float f; } v; v.i = ((unsigned int)u) << 16; return v.f;
}
__device__ __forceinline__ u16 f2b(float f) {
    union { float f; unsigned int i; } v; v.f = f;
    unsigned int x = v.i;
    return (u16)((x + 0x7fffu + ((x >> 16) & 1u)) >> 16);   // RNE
}
__device__ __forceinline__ u16 f2bf(float f) {
    return __builtin_bit_cast(u16, (__bf16)f);              // RNE via HW cvt
}

// ---------------------------------------------------------------------------
// On-device dtype probe. Requires blockDim >= 128. Returns 1 if bf16.
// ---------------------------------------------------------------------------
__device__ __forceinline__ int sane16(u16 u) {
    if (u == 0) return 1;
    int e = (u >> 7) & 0xFF;
    return (e >= 0x66 && e <= 0x8F);
}
__device__ __forceinline__ int probe_bf16(const void* base, int* sh) {
    int t = threadIdx.x;
    if (t == 0) { sh[0] = 0; sh[1] = 0; }
    __syncthreads();
    if (t < 128) {
        ushort4 v = ((const ushort4*)base)[t];
        int nz = (v.x != 0) + (v.y != 0) + (v.z != 0) + (v.w != 0);
        int fp = ((sane16(v.y) && (v.x == 0 || !sane16(v.x))) ? 1 : 0)
               + ((sane16(v.w) && (v.z == 0 || !sane16(v.z))) ? 1 : 0);
        if (nz) atomicAdd(&sh[1], nz);
        if (fp) atomicAdd(&sh[0], fp);
    }
    __syncthreads();
    int fpcnt = sh[0], nzcnt = sh[1];
    if (nzcnt == 0) return 1;
    return (fpcnt < 128) ? 1 : 0;
}
__device__ __forceinline__ float ld_in(const void* base, long idx, int isbf) {
    return isbf ? b2f(((const u16*)base)[idx]) : ((const float*)base)[idx];
}

// ---------------------------------------------------------------------------
// Embedding: x[b,s,:] = emb[ids[b,s],:] + pos[s,:]
// ---------------------------------------------------------------------------
__global__ __launch_bounds__(256) void k_embed(const int* __restrict__ ids,
                                               const void* __restrict__ emb,
                                               const void* __restrict__ pos,
                                               float* __restrict__ x) {
    __shared__ int psh[4];
    int ef = probe_bf16(emb, &psh[0]);
    int pf = probe_bf16(pos, &psh[2]);
    int row = blockIdx.x;
    int s   = row & (Sv - 1);
    long eb = (long)ids[row] * Hv;
    long pb = (long)s * Hv;
    float* o = x + (size_t)row * Hv;
    for (int h = threadIdx.x; h < Hv; h += 256)
        o[h] = ld_in(emb, eb + h, ef) + ld_in(pos, pb + h, pf);
}

// ---------------------------------------------------------------------------
// fp32x4 -> bf16x4 RNE via compiler conversion (emits v_cvt_pk_bf16_f32).
// ---------------------------------------------------------------------------
__device__ __forceinline__ ushort4 cvt4(float4 v) {
    ushort4 r;
    r.x = f2bf(v.x); r.y = f2bf(v.y); r.z = f2bf(v.z); r.w = f2bf(v.w);
    return r;
}

__device__ __forceinline__ f32x4 mfma16(u16x8 a, u16x8 b, f32x4 c) {
    return __builtin_amdgcn_mfma_f32_16x16x32_bf16(
        __builtin_bit_cast(bf16x8, a), __builtin_bit_cast(bf16x8, b), c, 0, 0, 0);
}

// ---------------------------------------------------------------------------
// Single-pass bf16 MFMA GEMM: C[M,N] = A[M,K] @ W[N,K]^T (+bias)(+GELU epi).
// ---------------------------------------------------------------------------
template<int BM, int BN>
__global__ __launch_bounds__(256) void k_gemm_t(
    const float* __restrict__ A,
    const void* __restrict__ Wb, long Woff,
    const void* __restrict__ Bb, long Boff, int has_bias,
    float* __restrict__ C, int M, int N, int K, int epi, int to_out)
{
    constexpr int FM = BM / 32, FN = BN / 32;   // 16x16 frags per wave (M,N)
    constexpr int NA = BM / 64, NW = BN / 64;   // staged row-iters per thread
    __shared__ __align__(16) u16 Ah[BM * LDW];
    __shared__ __align__(16) u16 Wh[BN * LDW];
    __shared__ int psh[4];
    const int wf  = probe_bf16(Wb, &psh[0]);
    const int bfl = has_bias ? probe_bf16(Bb, &psh[2]) : 0;

    const int bm = blockIdx.y * BM, bn = blockIdx.x * BN;
    const int tid  = threadIdx.x;
    const int lane = tid & 63, wid = tid >> 6;
    const int wm = (wid >> 1) * (BM / 2), wn = (wid & 1) * (BN / 2);
    const int fr = lane & 15, fc = lane >> 4;
    const int r0 = tid >> 2, c0 = tid & 3;      // staging row / 8-elem chunk

    f32x4 acc[FM][FN];
#pragma unroll
    for (int i = 0; i < FM; ++i)
#pragma unroll
        for (int j = 0; j < FN; ++j) acc[i][j] = (f32x4){0.f, 0.f, 0.f, 0.f};

    for (int k0 = 0; k0 < K; k0 += 32) {
        const int kk = k0 + c0 * 8;
        ushort4 as[NA][2], ws[NW][2];
#pragma unroll
        for (int ia = 0; ia < NA; ++ia) {
            const float* p = A + (size_t)(bm + r0 + 64 * ia) * K + kk;
            as[ia][0] = cvt4(*(const float4*)p);
            as[ia][1] = cvt4(*(const float4*)(p + 4));
        }
#pragma unroll
        for (int iw = 0; iw < NW; ++iw) {
            const size_t wrow = (size_t)Woff + (size_t)(bn + r0 + 64 * iw) * K + kk;
            if (wf) {
                const u16* p = (const u16*)Wb + wrow;
                ws[iw][0] = *(const ushort4*)p;
                ws[iw][1] = *(const ushort4*)(p + 4);
            } else {
                const float* p = (const float*)Wb + wrow;
                ws[iw][0] = cvt4(*(const float4*)p);
                ws[iw][1] = cvt4(*(const float4*)(p + 4));
            }
        }

        __syncthreads();                       // prev-tile readers done
#pragma unroll
        for (int ia = 0; ia < NA; ++ia) {
            const int o = (r0 + 64 * ia) * LDW + c0 * 8;
            *(ushort4*)&Ah[o]     = as[ia][0];
            *(ushort4*)&Ah[o + 4] = as[ia][1];
        }
#pragma unroll
        for (int iw = 0; iw < NW; ++iw) {
            const int o = (r0 + 64 * iw) * LDW + c0 * 8;
            *(ushort4*)&Wh[o]     = ws[iw][0];
            *(ushort4*)&Wh[o + 4] = ws[iw][1];
        }
        __syncthreads();

        u16x8 af[FM], wfr[FN];
#pragma unroll
        for (int mi = 0; mi < FM; ++mi)
            af[mi] = *(const u16x8*)&Ah[(wm + mi * 16 + fr) * LDW + fc * 8];
#pragma unroll
        for (int ni = 0; ni < FN; ++ni)
            wfr[ni] = *(const u16x8*)&Wh[(wn + ni * 16 + fr) * LDW + fc * 8];

#pragma unroll
        for (int mi = 0; mi < FM; ++mi)
#pragma unroll
            for (int ni = 0; ni < FN; ++ni)
                acc[mi][ni] = mfma16(af[mi], wfr[ni], acc[mi][ni]);
    }

    // ---- epilogue: C/D layout col=lane&15, row=(lane>>4)*4+reg ----
#pragma unroll
    for (int ni = 0; ni < FN; ++ni) {
        const int col = bn + wn + ni * 16 + fr;
        const float bias = has_bias ? ld_in(Bb, Boff + col, bfl) : 0.f;
#pragma unroll
        for (int mi = 0; mi < FM; ++mi) {
#pragma unroll
            for (int r = 0; r < 4; ++r) {
                const int row = bm + wm + mi * 16 + fc * 4 + r;
                float v = acc[mi][ni][r] + bias;
                if (epi == 1) v = 0.5f * v * (1.f + erff(v * 0.70710678118654752f));
                size_t idx = (size_t)row * N + col;
                if (to_out && wf) ((u16*)C)[idx] = f2b(v);
                else              C[idx] = v;
            }
        }
    }
}

// ---------------------------------------------------------------------------
// u = sigmoid(gpre) * ub
// ---------------------------------------------------------------------------
__global__ __launch_bounds__(256) void k_gate(const float* __restrict__ gpre,
                                              const float* __restrict__ ub,
                                              float* __restrict__ u, int n) {
    int i = blockIdx.x * 256 + threadIdx.x;
    if (i < n) {
        float s = 1.f / (1.f + expf(-gpre[i]));
        u[i] = s * ub[i];
    }
}

// ---------------------------------------------------------------------------
// Selective-scan: st[b,s,n] = A[n]*st[b,s-1,n] + u[b,s,n],  A = exp(A_log)
// ---------------------------------------------------------------------------
__global__ __launch_bounds__(128) void k_scan(const void* __restrict__ A_log, long off,
                                              const float* __restrict__ u,
                                              float* __restrict__ st) {
    __shared__ int psh[2];
    int af = probe_bf16(A_log, psh);
    int b = blockIdx.x, n = threadIdx.x;
    float A = expf(ld_in(A_log, off + n, af));
    const float* up = u  + (size_t)b * Sv * Nv + n;
    float*       sp = st + (size_t)b * Sv * Nv + n;
    float s = 0.f;
    for (int t = 0; t < Sv; ++t) {
        s = fmaf(A, s, up[(size_t)t * Nv]);
        sp[(size_t)t * Nv] = s;
    }
}

// ---------------------------------------------------------------------------
// y += (Dp[h]+1) * x
// ---------------------------------------------------------------------------
__global__ __launch_bounds__(256) void k_dx(float* __restrict__ y,
                                            const float* __restrict__ x,
                                            const void* __restrict__ Dp, long off) {
    __shared__ int psh[2];
    int df = probe_bf16(Dp, psh);
    int row = blockIdx.x;
    size_t base = (size_t)row * Hv;
    for (int h = threadIdx.x; h < Hv; h += 256)
        y[base + h] = fmaf(ld_in(Dp, off + h, df) + 1.f, x[base + h], y[base + h]);
}

// ---------------------------------------------------------------------------
// LayerNorm: out = postscale * ( LN(a (+ b)) * g + beta ), H=1024, eps=1e-5.
// ---------------------------------------------------------------------------
__global__ __launch_bounds__(256) void k_ln(const float* __restrict__ a,
                                            const float* __restrict__ b,
                                            const void* __restrict__ g, long goff,
                                            const void* __restrict__ bb, long boff,
                                            float* __restrict__ out,
                                            float postscale) {
    __shared__ float buf[Hv];
    __shared__ float red[4];
    __shared__ int psh[4];
    int gf_ = probe_bf16(g, &psh[0]);
    int bf_ = probe_bf16(bb, &psh[2]);
    int row = blockIdx.x, t = threadIdx.x;
    const float* ap = a + (size_t)row * Hv;
    const float* bp = b ? b + (size_t)row * Hv : nullptr;
    float ls = 0.f;
    for (int h = t; h < Hv; h += 256) {
        float v = ap[h] + (bp ? bp[h] : 0.f);
        buf[h] = v; ls += v;
    }
#pragma unroll
    for (int o = 32; o > 0; o >>= 1) ls += __shfl_down(ls, o, 64);
    if ((t & 63) == 0) red[t >> 6] = ls;
    __syncthreads();
    float mu = (red[0] + red[1] + red[2] + red[3]) * (1.f / Hv);
    __syncthreads();
    float lv = 0.f;
    for (int h = t; h < Hv; h += 256) { float d = buf[h] - mu; lv += d * d; }
#pragma unroll
    for (int o = 32; o > 0; o >>= 1) lv += __shfl_down(lv, o, 64);
    if ((t & 63) == 0) red[t >> 6] = lv;
    __syncthreads();
    float rstd = rsqrtf((red[0] + red[1] + red[2] + red[3]) * (1.f / Hv) + 1e-5f);
    for (int h = t; h < Hv; h += 256)
        out[(size_t)row * Hv + h] =
            ((buf[h] - mu) * rstd * ld_in(g, goff + h, gf_) + ld_in(bb, boff + h, bf_)) * postscale;
}

// ---------------------------------------------------------------------------
// MFMA q-tiled attention. Block = 32 q rows of one (b,h), 2 waves (16 q each).
// grid (S/32, NH, B) = (16,8,4). Phase A: S[16][512] per wave in 128 acc VGPRs
// (K staged in LDS chunks, layout = GEMM-proven stride-40), wave-local softmax
// via shfl_xor over lanes 0..15. P (scaled, bf16) -> LDS. Phase B: V staged
// TRANSPOSED (Vt chunks), PV MFMAs. Frag conventions identical to k_gemm_t.
// ---------------------------------------------------------------------------
#define PSTR 536            // P row stride (u16): rows 16B-aligned, ~2-way
#define KCH  2568           // K chunk stride (u16): 64*40 + 8 skew
#define VCH  5128           // Vt chunk stride (u16): 128*40 + 8 skew

__global__ __launch_bounds__(128) void k_attn2(const float* __restrict__ qkv,
                                               float* __restrict__ ao) {
    __shared__ __align__(16) u16 Pl[32 * PSTR];   // 34,304 B
    __shared__ __align__(16) u16 ST[4 * KCH];     // 20,544 B (>= 2*VCH)
    const int t = threadIdx.x;
    const int lane = t & 63, w = t >> 6;
    const int fr = lane & 15, fc = lane >> 4;
    const int qb = blockIdx.x * 32, h = blockIdx.y, b = blockIdx.z;
    const size_t rs = 3 * (size_t)Hv;
    const float* qkvb = qkv + (size_t)b * Sv * rs;
    const float* kb = qkvb + Hv + h * DHv;
    const float* vb = qkvb + 2 * Hv + h * DHv;

    // ---- Q fragments (pre-scaled by 1/sqrt(DH)) ----
    u16x8 aq[4];
    {
        const float* qp = qkvb + (size_t)(qb + w * 16 + fr) * rs + h * DHv + fc * 8;
        const float sc = 0.08838834764831845f;
#pragma unroll
        for (int c = 0; c < 4; ++c) {
            float4 x0 = *(const float4*)(qp + c * 32);
            float4 x1 = *(const float4*)(qp + c * 32 + 4);
            aq[c][0] = f2bf(x0.x * sc); aq[c][1] = f2bf(x0.y * sc);
            aq[c][2] = f2bf(x0.z * sc); aq[c][3] = f2bf(x0.w * sc);
            aq[c][4] = f2bf(x1.x * sc); aq[c][5] = f2bf(x1.y * sc);
            aq[c][6] = f2bf(x1.z * sc); aq[c][7] = f2bf(x1.w * sc);
        }
    }

    // ---- Phase A: S = Q K^T, acc s[f] holds k = f*16 + fr, q = fc*4 + r ----
    f32x4 s[32];
#pragma unroll
    for (int f = 0; f < 32; ++f) s[f] = (f32x4){0.f, 0.f, 0.f, 0.f};

#pragma unroll
    for (int kt = 0; kt < 8; ++kt) {
        __syncthreads();                       // prev-tile readers done
        // stage K rows kt*64..+63 -> 4 d-chunks [64][40]
#pragma unroll
        for (int rr = 0; rr < 2; ++rr) {
            const int kk = rr * 32 + (t >> 2);
            const float* kp = kb + (size_t)(kt * 64 + kk) * rs + (t & 3) * 32;
#pragma unroll
            for (int i = 0; i < 8; ++i) {
                ushort4 u = cvt4(*(const float4*)(kp + 4 * i));
                *(ushort4*)&ST[(t & 3) * KCH + kk * 40 + 4 * i] = u;
            }
        }
        __syncthreads();
#pragma unroll
        for (int nf = 0; nf < 4; ++nf) {
#pragma unroll
            for (int dc = 0; dc < 4; ++dc) {
                u16x8 bk = *(const u16x8*)&ST[dc * KCH + (nf * 16 + fr) * 40 + fc * 8];
                s[kt * 4 + nf] = mfma16(aq[dc], bk, s[kt * 4 + nf]);
            }
        }
    }

    // ---- wave-local softmax (row q = fc*4+r lives in lanes sharing fc) ----
    float inv4[4];
#pragma unroll
    for (int r = 0; r < 4; ++r) {
        float m = -3.0e38f;
#pragma unroll
        for (int f = 0; f < 32; ++f) m = fmaxf(m, s[f][r]);
#pragma unroll
        for (int msk = 1; msk < 16; msk <<= 1) m = fmaxf(m, __shfl_xor(m, msk, 64));
        float l = 0.f;
#pragma unroll
        for (int f = 0; f < 32; ++f) { float e = expf(s[f][r] - m); s[f][r] = e; l += e; }
#pragma unroll
        for (int msk = 1; msk < 16; msk <<= 1) l += __shfl_xor(l, msk, 64);
        inv4[r] = 1.f / l;
    }
    // ---- P -> LDS (bf16, normalized); wave-private rows w*16..w*16+15 ----
    {
        u16* pw = &Pl[(w * 16 + fc * 4) * PSTR + fr];
#pragma unroll
        for (int r = 0; r < 4; ++r)
#pragma unroll
            for (int f = 0; f < 32; ++f)
                pw[r * PSTR + f * 16] = f2bf(s[f][r] * inv4[r]);
    }

    // ---- Phase B: O = P V  (V staged transposed, k-tiles of 64) ----
    f32x4 o[8];
#pragma unroll
    for (int d = 0; d < 8; ++d) o[d] = (f32x4){0.f, 0.f, 0.f, 0.f};

    for (int vt = 0; vt < 8; ++vt) {
        __syncthreads();                       // phase-A K / prev Vt readers done
        {
            const int p  = t >> 2;             // 0..31 -> k-pair
            const int kc = p >> 4;             // Vt chunk
            const int kl = (2 * p) & 31;
            const float* v0 = vb + (size_t)(vt * 64 + 2 * p) * rs + (t & 3) * 32;
            const float* v1 = v0 + rs;
#pragma unroll
            for (int i = 0; i < 8; ++i) {
                float4 a  = *(const float4*)(v0 + 4 * i);
                float4 b4 = *(const float4*)(v1 + 4 * i);
                const int d0 = (t & 3) * 32 + 4 * i;
                ushort2 w0; w0.x = f2bf(a.x); w0.y = f2bf(b4.x);
                ushort2 w1; w1.x = f2bf(a.y); w1.y = f2bf(b4.y);
                ushort2 w2; w2.x = f2bf(a.z); w2.y = f2bf(b4.z);
                ushort2 w3; w3.x = f2bf(a.w); w3.y = f2bf(b4.w);
                *(ushort2*)&ST[kc * VCH + (d0 + 0) * 40 + kl] = w0;
                *(ushort2*)&ST[kc * VCH + (d0 + 1) * 40 + kl] = w1;
                *(ushort2*)&ST[kc * VCH + (d0 + 2) * 40 + kl] = w2;
                *(ushort2*)&ST[kc * VCH + (d0 + 3) * 40 + kl] = w3;
            }
        }
        __syncthreads();
#pragma unroll
        for (int kc2 = 0; kc2 < 2; ++kc2) {
            u16x8 pf = *(const u16x8*)&Pl[(w * 16 + fr) * PSTR + vt * 64 + kc2 * 32 + fc * 8];
#pragma unroll
            for (int df = 0; df < 8; ++df) {
                u16x8 bv = *(const u16x8*)&ST[kc2 * VCH + (df * 16 + fr) * 40 + fc * 8];
                o[df] = mfma16(pf, bv, o[df]);
            }
        }
    }

    // ---- write out: row q = fc*4+r, col d = df*16+fr ----
#pragma unroll
    for (int df = 0; df < 8; ++df) {
        float* op = ao + (size_t)(b * Sv + qb + w * 16 + fc * 4) * Hv + h * DHv + df * 16 + fr;
#pragma unroll
        for (int r = 0; r < 4; ++r)
            op[(size_t)r * Hv] = o[df][r];
    }
}

// ---------------------------------------------------------------------------
extern "C" void kernel_launch(void* const* d_in, const int* in_sizes, int n_in,
                              void* d_out, int out_size, void* d_ws, size_t ws_size,
                              hipStream_t stream) {
    const int*  ids   = (const int*)d_in[0];
    const void *emb = d_in[1], *pos = d_in[2], *A_log = d_in[3], *WB = d_in[4],
               *WC = d_in[5], *Dp = d_in[6], *Wg = d_in[7], *bg = d_in[8],
               *Wout = d_in[9], *bout = d_in[10], *gs = d_in[11], *bs = d_in[12],
               *Wqkv = d_in[13], *bqkv = d_in[14], *Wo = d_in[15], *bo = d_in[16],
               *W1 = d_in[17], *b1 = d_in[18], *W2 = d_in[19], *b2 = d_in[20],
               *g1 = d_in[21], *bn1 = d_in[22], *g2 = d_in[23], *bn2 = d_in[24],
               *g3 = d_in[25], *bn3 = d_in[26], *gf = d_in[27], *bf = d_in[28];

    // Scratch: front 56 MB of d_out (dead before the final GEMM overwrites all
    // of d_out). FINAL (read while d_out is written) lives in d_ws (8 MB).
    char* ob = (char*)d_out;
    float* X   = (float*)(ob + 0);          //  8 MB  [2048,1024]
    float* T1  = (float*)(ob + 8388608);    //  8 MB  [2048,1024]
    float* T2  = (float*)(ob + 16777216);   //  8 MB  [2048,1024]
    float* FH  = (float*)(ob + 25165824);   // 32 MB  [2048,4096]
    float* QKV = FH;                        // 24 MB  [2048,3072]  (aliased)
    float* G   = FH;                        //  1 MB  [2048,128]   (aliased)
    float* U   = (float*)(ob + 25165824 + 1048576);
    float* ST  = (float*)(ob + 25165824 + 2097152);
    float* FINAL = (float*)d_ws;            //  8 MB  [2048,1024]

    auto gemm = [&](const float* A, const void* W, long Woff, const void* bias, long Boff,
                    int hasb, float* C, int M, int N, int K, int epi, int to_out) {
        if (N >= 3072) {
            dim3 grid(N / 128, M / 128);
            k_gemm_t<128,128><<<grid, 256, 0, stream>>>(A, W, Woff, bias, Boff, hasb, C, M, N, K, epi, to_out);
        } else if (N >= 1024) {
            dim3 grid(N / 64, M / 128);
            k_gemm_t<128,64><<<grid, 256, 0, stream>>>(A, W, Woff, bias, Boff, hasb, C, M, N, K, epi, to_out);
        } else {
            dim3 grid(N / 64, M / 64);
            k_gemm_t<64,64><<<grid, 256, 0, stream>>>(A, W, Woff, bias, Boff, hasb, C, M, N, K, epi, to_out);
        }
    };

    k_embed<<<Mv, 256, 0, stream>>>(ids, emb, pos, X);

    for (int i = 0; i < Lv; ++i) {
        long oNH = (long)i * Nv * Hv, oHN = (long)i * Hv * Nv, oHH = (long)i * Hv * Hv;
        long oN = (long)i * Nv, oH = (long)i * Hv;

        // --- SSM block ---
        gemm(X, Wg, oNH, bg, oN, 1, G, Mv, Nv, Hv, 0, 0);           // gate pre-act
        gemm(X, WB, oNH, nullptr, 0, 0, U, Mv, Nv, Hv, 0, 0);       // B proj
        k_gate<<<(Mv * Nv) / 256, 256, 0, stream>>>(G, U, U, Mv * Nv);
        k_scan<<<Bv, 128, 0, stream>>>(A_log, oN, U, ST);
        gemm(ST, WC, oHN, nullptr, 0, 0, T1, Mv, Hv, Nv, 0, 0);     // y = st @ WC^T
        k_dx<<<Mv, 256, 0, stream>>>(T1, X, Dp, oH);                // += (Dp+1)*x
        k_ln<<<Mv, 256, 0, stream>>>(T1, nullptr, gs, oH, bs, oH, T2, 1.f);
        gemm(T2, Wout, oHH, bout, oH, 1, T1, Mv, Hv, Hv, 0, 0);     // xs
        k_ln<<<Mv, 256, 0, stream>>>(X, T1, g1, oH, bn1, oH, X, 1.f);

        // --- attention (odd layers); HierarchicalMemory x2 folds into LN postscale ---
        if (i & 1) {
            gemm(X, Wqkv, 3 * oHH, bqkv, 3 * oH, 1, QKV, Mv, 3 * Hv, Hv, 0, 0);
            dim3 ag(Sv / 32, NHv, Bv);
            k_attn2<<<ag, 128, 0, stream>>>(QKV, T1);
            gemm(T1, Wo, oHH, bo, oH, 1, T2, Mv, Hv, Hv, 0, 0);
            k_ln<<<Mv, 256, 0, stream>>>(X, T2, g2, oH, bn2, oH, X, 2.f);
        } else {
            k_ln<<<Mv, 256, 0, stream>>>(X, nullptr, g2, oH, bn2, oH, X, 2.f);
        }

        // --- FFN ---
        gemm(X, W1, (long)i * FFv * Hv, b1, (long)i * FFv, 1, FH, Mv, FFv, Hv, 1, 0);
        gemm(FH, W2, (long)i * Hv * FFv, b2, oH, 1, T1, Mv, Hv, FFv, 0, 0);
        k_ln<<<Mv, 256, 0, stream>>>(X, T1, g3, oH, bn3, oH, X, 1.f);
    }

    // --- final LN (into d_ws) + tied lm_head (dtype follows emb; fills d_out) ---
    k_ln<<<Mv, 256, 0, stream>>>(X, nullptr, gf, 0, bf, 0, FINAL, 1.f);
    gemm(FINAL, emb, 0, nullptr, 0, 0, (float*)d_out, Mv, Vv, Hv, 0, 1);
}